// Round 11
// baseline (396.828 us; speedup 1.0000x reference)
//
#include <hip/hip_runtime.h>
#include <hip/hip_bf16.h>

#define NB 8
#define NT 256
#define NL 64
#define ND 768

typedef __attribute__((ext_vector_type(4))) float f32x4;
typedef __attribute__((ext_vector_type(8))) short bf16x8;

__device__ __forceinline__ short f2bs(float f) {
    __hip_bfloat16 h = __float2bfloat16(f);
    return *reinterpret_cast<short*>(&h);
}
__device__ __forceinline__ unsigned pack2(float a, float b) {
    return (unsigned)(ushort)f2bs(a) | ((unsigned)(ushort)f2bs(b) << 16);
}
__device__ __forceinline__ bf16x8 cvt8(float4 x, float4 y) {
    bf16x8 r;
    r[0] = f2bs(x.x); r[1] = f2bs(x.y); r[2] = f2bs(x.z); r[3] = f2bs(x.w);
    r[4] = f2bs(y.x); r[5] = f2bs(y.y); r[6] = f2bs(y.z); r[7] = f2bs(y.w);
    return r;
}

// raw barrier: LDS-writes fenced, global loads stay in flight (no vmcnt drain)
__device__ __forceinline__ void bar_lds() {
    asm volatile("s_waitcnt lgkmcnt(0)" ::: "memory");
    __builtin_amdgcn_s_barrier();
    asm volatile("" ::: "memory");
}
__device__ __forceinline__ void bar_only() {
    asm volatile("" ::: "memory");
    __builtin_amdgcn_s_barrier();
    asm volatile("" ::: "memory");
}

// ---------------- Kernel 1: k/v projections, bf16 MFMA ----------------------
__global__ __launch_bounds__(256, 4) void projb_kernel(
    const float* __restrict__ E, const float* __restrict__ Wk,
    const float* __restrict__ Wv, ushort* __restrict__ kb,
    ushort* __restrict__ vb)
{
    const float* W = (blockIdx.z == 0) ? Wk : Wv;
    ushort* O      = (blockIdx.z == 0) ? kb : vb;
    const int m0 = blockIdx.x * 64;
    const int e0 = blockIdx.y * 64;

    __shared__ ushort At[4096];   // E slab [64 m][64 d] bf16, swizzled
    __shared__ ushort Wt[4096];   // W slab [64 e][64 d] bf16, swizzled
    __shared__ ushort Sb[4096];

    const int tid = threadIdx.x;
    const int lane = tid & 63, w = tid >> 6;
    const int fr = lane & 15;
    const int fq = lane >> 4;
    const int row2 = tid >> 4;      // 0..15 tok-staging row base
    const int c4   = tid & 15;      // float4 col
    const int arow = w * 16 + fr;
    const int asw  = (arow & 7) << 3;

    const f32x4 z4 = {0.f, 0.f, 0.f, 0.f};

    f32x4 accS[4];
    #pragma unroll
    for (int jt = 0; jt < 4; ++jt) accS[jt] = z4;

    float4 ea[2][4], wa[2][4];
    #pragma unroll
    for (int p = 0; p < 4; ++p) {
        ea[0][p] = *(const float4*)(E + (size_t)(m0 + row2 + 16 * p) * ND + c4 * 4);
        wa[0][p] = *(const float4*)(W + (size_t)(e0 + row2 + 16 * p) * ND + c4 * 4);
    }

    #pragma unroll
    for (int dt = 0; dt < 12; ++dt) {
        const int cur = dt & 1, nxt = cur ^ 1;
        #pragma unroll
        for (int p = 0; p < 4; ++p) {
            const int r = row2 + 16 * p;
            const int uidx = (r * 64 + c4 * 4) ^ ((r & 7) << 3);
            uint2 te; te.x = pack2(ea[cur][p].x, ea[cur][p].y); te.y = pack2(ea[cur][p].z, ea[cur][p].w);
            uint2 tw; tw.x = pack2(wa[cur][p].x, wa[cur][p].y); tw.y = pack2(wa[cur][p].z, wa[cur][p].w);
            *(uint2*)&At[uidx] = te;
            *(uint2*)&Wt[uidx] = tw;
        }
        if (dt < 11) {
            const int c0 = (dt + 1) * 64 + c4 * 4;
            #pragma unroll
            for (int p = 0; p < 4; ++p) {
                ea[nxt][p] = *(const float4*)(E + (size_t)(m0 + row2 + 16 * p) * ND + c0);
                wa[nxt][p] = *(const float4*)(W + (size_t)(e0 + row2 + 16 * p) * ND + c0);
            }
        }
        bar_lds();
        #pragma unroll
        for (int ks = 0; ks < 2; ++ks) {
            bf16x8 af = *(const bf16x8*)&At[(arow * 64 + ks * 32 + fq * 8) ^ asw];
            #pragma unroll
            for (int jt = 0; jt < 4; ++jt) {
                const int brow = jt * 16 + fr;
                bf16x8 bv = *(const bf16x8*)&Wt[(brow * 64 + ks * 32 + fq * 8) ^ ((brow & 7) << 3)];
                accS[jt] = __builtin_amdgcn_mfma_f32_16x16x32_bf16(af, bv, accS[jt], 0, 0, 0);
            }
        }
        bar_only();
    }

    #pragma unroll
    for (int jt = 0; jt < 4; ++jt)
        #pragma unroll
        for (int i = 0; i < 4; ++i) {
            const int r = w * 16 + fq * 4 + i;
            const int c = jt * 16 + fr;
            Sb[(r * 64 + c) ^ ((r & 7) << 3)] = (ushort)f2bs(accS[jt][i]);
        }
    bar_lds();
    #pragma unroll
    for (int g = 0; g < 2; ++g) {
        const int c = g * 256 + tid;
        const int r = c >> 3, col8 = c & 7;
        uint4 v = *(const uint4*)&Sb[(r * 64 + col8 * 8) ^ ((r & 7) << 3)];
        *(uint4*)(O + (size_t)(m0 + r) * ND + e0 + col8 * 8) = v;
    }
}

// ---------------- Kernel 2a: S = tok @ v^T (coalesced staged, raw barriers) --
__global__ __launch_bounds__(256, 4) void s_kernel(
    const int* __restrict__ spk, const float* __restrict__ tok,
    const ushort* __restrict__ vws, ushort* __restrict__ S_ws,
    int* __restrict__ mlistw)
{
    __shared__ int mlist[NT];
    __shared__ int wavecnt[4];
    __shared__ ushort At[4096];      // tok slab [64 l][64 d] bf16, swizzled
    __shared__ ushort Vt[4096];      // v   slab [64 j][64 d] bf16, swizzled
    __shared__ ushort Sb[4096];

    const int bt  = (blockIdx.x & 7) * 256 + (blockIdx.x >> 3);  // XCD swizzle
    const int b   = bt >> 8;
    const int t   = bt & 255;
    const int tid = threadIdx.x;

    const int tgt = spk[b * NT + t];
    int my = -1;
    if (tid <= t) my = spk[b * NT + tid];
    const bool match = (tid <= t) && (my == tgt);
    unsigned long long bal = __ballot(match);
    const int lane = tid & 63, w = tid >> 6;
    if (lane == 0) wavecnt[w] = __popcll(bal);
    __syncthreads();
    int off = 0;
    #pragma unroll
    for (int ww = 0; ww < 4; ++ww) if (ww < w) off += wavecnt[ww];
    const int n = wavecnt[0] + wavecnt[1] + wavecnt[2] + wavecnt[3];
    const int before = __popcll(bal & ((1ull << lane) - 1ull));
    if (match) mlist[off + before] = tid;
    __syncthreads();

    mlistw[bt * 260 + tid] = (tid < n) ? mlist[tid] : 0;
    if (tid == 0) mlistw[bt * 260 + 256] = n;

    const int fr = lane & 15;
    const int fq = lane >> 4;
    const int row2 = tid >> 4;       // tok staging: 16 lanes/row
    const int c4   = tid & 15;
    const int vrow = tid >> 2;       // v staging: 4 lanes/row
    const int q    = tid & 3;
    const int vsw  = (vrow & 7) << 3;
    const int arow = w * 16 + fr;
    const int asw  = (arow & 7) << 3;

    const size_t tokbase = (size_t)bt * NL * ND;
    const ushort* vbase = vws + (size_t)b * NT * ND;
    const f32x4 z4 = {0.f, 0.f, 0.f, 0.f};

    const int nchunk = (n + 63) >> 6;
    for (int cc = 0; cc < nchunk; ++cc) {
        const int j0 = cc * 64;
        const int jj = j0 + vrow;
        const ushort* gv = vbase + (size_t)mlist[jj < n ? jj : n - 1] * ND;

        f32x4 accS[4];
        #pragma unroll
        for (int jt = 0; jt < 4; ++jt) accS[jt] = z4;

        float4 ta[2][4];
        uint4 vu[2][2];
        #pragma unroll
        for (int p = 0; p < 4; ++p)
            ta[0][p] = *(const float4*)(tok + tokbase + (size_t)(row2 + 16 * p) * ND + c4 * 4);
        vu[0][0] = *(const uint4*)(gv + q * 16);
        vu[0][1] = *(const uint4*)(gv + q * 16 + 8);

        #pragma unroll
        for (int dt = 0; dt < 12; ++dt) {
            const int cur = dt & 1, nxt = cur ^ 1;
            #pragma unroll
            for (int p = 0; p < 4; ++p) {
                const int r = row2 + 16 * p;
                const int uidx = (r * 64 + c4 * 4) ^ ((r & 7) << 3);
                uint2 tw; tw.x = pack2(ta[cur][p].x, ta[cur][p].y);
                tw.y = pack2(ta[cur][p].z, ta[cur][p].w);
                *(uint2*)&At[uidx] = tw;
            }
            *(uint4*)&Vt[vrow * 64 + ((q * 16) ^ vsw)]     = vu[cur][0];
            *(uint4*)&Vt[vrow * 64 + ((q * 16 + 8) ^ vsw)] = vu[cur][1];
            if (dt < 11) {   // prefetch next slab; stays in flight across barriers
                const int c0 = (dt + 1) * 64;
                #pragma unroll
                for (int p = 0; p < 4; ++p)
                    ta[nxt][p] = *(const float4*)(tok + tokbase + (size_t)(row2 + 16 * p) * ND + c0 + c4 * 4);
                vu[nxt][0] = *(const uint4*)(gv + c0 + q * 16);
                vu[nxt][1] = *(const uint4*)(gv + c0 + q * 16 + 8);
            }
            bar_lds();
            #pragma unroll
            for (int ks = 0; ks < 2; ++ks) {
                bf16x8 af = *(const bf16x8*)&At[(arow * 64 + ks * 32 + fq * 8) ^ asw];
                #pragma unroll
                for (int jt = 0; jt < 4; ++jt) {
                    const int brow = jt * 16 + fr;
                    bf16x8 bv = *(const bf16x8*)&Vt[brow * 64 + ((ks * 32 + fq * 8) ^ ((brow & 7) << 3))];
                    accS[jt] = __builtin_amdgcn_mfma_f32_16x16x32_bf16(af, bv, accS[jt], 0, 0, 0);
                }
            }
            bar_only();
        }

        #pragma unroll
        for (int jt = 0; jt < 4; ++jt)
            #pragma unroll
            for (int i = 0; i < 4; ++i) {
                const int r = w * 16 + fq * 4 + i;
                const int c = jt * 16 + fr;
                Sb[(r * 64 + c) ^ ((r & 7) << 3)] = (ushort)f2bs(accS[jt][i]);
            }
        bar_lds();
        ushort* dst = S_ws + ((size_t)bt * 4 + cc) * 4096;
        #pragma unroll
        for (int g = 0; g < 2; ++g) {
            const int wsg = g * 256 + tid;
            const int r = wsg >> 3, c8 = wsg & 7;
            *(f32x4*)&dst[(size_t)wsg * 8] = *(const f32x4*)&Sb[(r * 64 + c8 * 8) ^ ((r & 7) << 3)];
        }
        bar_only();
    }
}

// ---------------- Kernel 2b: out = tok + S @ K (line-contiguous k gather) ---
__global__ __launch_bounds__(256, 4) void b_kernel(
    const float* __restrict__ tok, const ushort* __restrict__ kws,
    const ushort* __restrict__ S_ws, const int* __restrict__ mlistw,
    float* __restrict__ out)
{
    __shared__ ushort Sb[4096];
    __shared__ ushort kT[8192];

    const int i = blockIdx.x;
    const int wgid = (i & 7) * 1536 + (i >> 3);   // XCD swizzle (bijective)
    const int bt = wgid / 6;
    const int st = wgid % 6;
    const int b   = bt >> 8;
    const int tid = threadIdx.x;
    const int lane = tid & 63, w = tid >> 6;

    const int n = mlistw[bt * 260 + 256];

    const int fr = lane & 15;
    const int fq = lane >> 4;
    const int jr = tid >> 2;       // k-row owner (0..63)
    const int q  = tid & 3;        // 4 lanes contiguous within a line
    const size_t tokbase = (size_t)bt * NL * ND;
    const ushort* kbase = kws + (size_t)b * NT * ND;

    // residual init at C-layout positions (full 64B lines per 16-lane group)
    f32x4 acco[8];
    {
        const float* rbp = tok + tokbase + (size_t)(w * 16 + fq * 4) * ND + st * 128 + fr;
        #pragma unroll
        for (int ct = 0; ct < 8; ++ct)
            #pragma unroll
            for (int i2 = 0; i2 < 4; ++i2)
                acco[ct][i2] = rbp[(size_t)i2 * ND + ct * 16];
    }

    const int nchunk = (n + 63) >> 6;
    for (int cc = 0; cc < nchunk; ++cc) {
        const int j0 = cc * 64;
        const ushort* src = S_ws + ((size_t)bt * 4 + cc) * 4096;
        f32x4 sv0 = *(const f32x4*)&src[(size_t)tid * 8];
        f32x4 sv1 = *(const f32x4*)&src[(size_t)(256 + tid) * 8];
        const int jj = j0 + jr;
        const int g = (jj < n) ? mlistw[bt * 260 + jj] : -1;
        uint4 kq[4];
        const uint4 zu = {0u, 0u, 0u, 0u};
        #pragma unroll
        for (int u = 0; u < 4; ++u)
            kq[u] = (g >= 0)
                ? *(const uint4*)(kbase + (size_t)g * ND + st * 128 + u * 32 + q * 8)
                : zu;

        if (cc > 0) bar_only();
        {
            int wsg = tid, r = wsg >> 3, c8 = wsg & 7;
            *(f32x4*)&Sb[(r * 64 + c8 * 8) ^ ((r & 7) << 3)] = sv0;
            wsg = 256 + tid; r = wsg >> 3; c8 = wsg & 7;
            *(f32x4*)&Sb[(r * 64 + c8 * 8) ^ ((r & 7) << 3)] = sv1;
        }
        {
            const ushort* pk = (const ushort*)kq;
            #pragma unroll
            for (int u = 0; u < 4; ++u)
                #pragma unroll
                for (int e = 0; e < 8; ++e) {
                    const int dc = u * 32 + q * 8 + e;
                    kT[(dc * 64 + jr) ^ ((dc & 7) << 3)] = pk[u * 8 + e];
                }
        }
        bar_lds();

        const int arow = w * 16 + fr;
        #pragma unroll
        for (int ks = 0; ks < 2; ++ks) {
            bf16x8 af = *(const bf16x8*)&Sb[(arow * 64 + ks * 32 + fq * 8) ^ ((arow & 7) << 3)];
            #pragma unroll
            for (int ct = 0; ct < 8; ++ct) {
                const int brow = ct * 16 + fr;
                bf16x8 bv = *(const bf16x8*)&kT[(brow * 64 + ks * 32 + fq * 8) ^ ((brow & 7) << 3)];
                acco[ct] = __builtin_amdgcn_mfma_f32_16x16x32_bf16(af, bv, acco[ct], 0, 0, 0);
            }
        }
    }

    float* ob = out + tokbase + (size_t)(w * 16 + fq * 4) * ND + st * 128 + fr;
    #pragma unroll
    for (int ct = 0; ct < 8; ++ct)
        #pragma unroll
        for (int i2 = 0; i2 < 4; ++i2)
            ob[(size_t)i2 * ND + ct * 16] = acco[ct][i2];
}

extern "C" void kernel_launch(void* const* d_in, const int* in_sizes, int n_in,
                              void* d_out, int out_size, void* d_ws, size_t ws_size,
                              hipStream_t stream) {
    const int*   spk = (const int*)d_in[1];
    const float* tok = (const float*)d_in[2];
    const float* edu = (const float*)d_in[3];
    const float* Wk  = (const float*)d_in[4];
    const float* Wv  = (const float*)d_in[5];

    const size_t kv_elems = (size_t)NB * NT * ND;
    ushort* kb = (ushort*)d_ws;
    ushort* vb = kb + kv_elems;
    ushort* S_ws = vb + kv_elems;
    int* mlistw = (int*)(S_ws + (size_t)NB * NT * 4 * 4096);
    float* outp = (float*)d_out;

    projb_kernel<<<dim3(2048 / 64, ND / 64, 2), 256, 0, stream>>>(edu, Wk, Wv, kb, vb);
    s_kernel<<<NB * NT, 256, 0, stream>>>(spk, tok, vb, S_ws, mlistw);
    b_kernel<<<NB * NT * 6, 256, 0, stream>>>(tok, kb, S_ws, mlistw, outp);
}

// Round 12
// 323.974 us; speedup vs baseline: 1.2249x; 1.2249x over previous
//
#include <hip/hip_runtime.h>
#include <hip/hip_bf16.h>

#define NB 8
#define NT 256
#define NL 64
#define ND 768

typedef __attribute__((ext_vector_type(4))) float f32x4;
typedef __attribute__((ext_vector_type(8))) short bf16x8;

__device__ __forceinline__ short f2bs(float f) {
    __hip_bfloat16 h = __float2bfloat16(f);
    return *reinterpret_cast<short*>(&h);
}
__device__ __forceinline__ unsigned pack2(float a, float b) {
    return (unsigned)(ushort)f2bs(a) | ((unsigned)(ushort)f2bs(b) << 16);
}

// ---------------- Kernel 1: k/v projections via bf16 MFMA, f32 outputs ------
// O[m,e] = sum_d E[m,d]*W[e,d].  A=W-tiles (i=e), B=E-tiles (j=m) so the
// C-layout gives each lane 4 consecutive e-cols of one m-row -> float4 store.
__global__ __launch_bounds__(256, 4) void projm_kernel(
    const float* __restrict__ E, const float* __restrict__ Wk,
    const float* __restrict__ Wv, float* __restrict__ kws,
    float* __restrict__ vws)
{
    const float* W = (blockIdx.z == 0) ? Wk : Wv;
    float* O       = (blockIdx.z == 0) ? kws : vws;
    const int m0 = blockIdx.x * 64;
    const int e0 = blockIdx.y * 64;

    __shared__ ushort Et[2][4096];   // E slab [64 m][64 d] bf16, swizzled
    __shared__ ushort Wt[2][4096];   // W slab [64 e][64 d] bf16, swizzled

    const int tid = threadIdx.x;
    const int lane = tid & 63, w = tid >> 6;
    const int fr = lane & 15;
    const int fq = lane >> 4;
    const int row2 = tid >> 4;       // staging row base 0..15 (16 lanes/row)
    const int c4   = tid & 15;       // float4 col

    const f32x4 z4 = {0.f, 0.f, 0.f, 0.f};
    f32x4 acc[4];
    #pragma unroll
    for (int et = 0; et < 4; ++et) acc[et] = z4;

    float4 ea[2][4], wa[2][4];
    #pragma unroll
    for (int p = 0; p < 4; ++p) {
        ea[0][p] = *(const float4*)(E + (size_t)(m0 + row2 + 16 * p) * ND + c4 * 4);
        wa[0][p] = *(const float4*)(W + (size_t)(e0 + row2 + 16 * p) * ND + c4 * 4);
    }

    #pragma unroll
    for (int dt = 0; dt < 12; ++dt) {
        const int cur = dt & 1, nxt = cur ^ 1;
        #pragma unroll
        for (int p = 0; p < 4; ++p) {
            const int r = row2 + 16 * p;
            const int uidx = (r * 64 + c4 * 4) ^ ((r & 7) << 3);
            uint2 te; te.x = pack2(ea[cur][p].x, ea[cur][p].y); te.y = pack2(ea[cur][p].z, ea[cur][p].w);
            uint2 tw; tw.x = pack2(wa[cur][p].x, wa[cur][p].y); tw.y = pack2(wa[cur][p].z, wa[cur][p].w);
            *(uint2*)&Et[cur][uidx] = te;
            *(uint2*)&Wt[cur][uidx] = tw;
        }
        if (dt < 11) {
            const int c0 = (dt + 1) * 64 + c4 * 4;
            #pragma unroll
            for (int p = 0; p < 4; ++p) {
                ea[nxt][p] = *(const float4*)(E + (size_t)(m0 + row2 + 16 * p) * ND + c0);
                wa[nxt][p] = *(const float4*)(W + (size_t)(e0 + row2 + 16 * p) * ND + c0);
            }
        }
        __syncthreads();
        const int brow = w * 16 + fr;                  // B = E rows (m)
        const int bsw  = (brow & 7) << 3;
        #pragma unroll
        for (int ks = 0; ks < 2; ++ks) {
            bf16x8 bv = *(const bf16x8*)&Et[cur][(brow * 64 + ks * 32 + fq * 8) ^ bsw];
            #pragma unroll
            for (int et = 0; et < 4; ++et) {
                const int arow = et * 16 + fr;         // A = W rows (e)
                bf16x8 af = *(const bf16x8*)&Wt[cur][(arow * 64 + ks * 32 + fq * 8) ^ ((arow & 7) << 3)];
                acc[et] = __builtin_amdgcn_mfma_f32_16x16x32_bf16(af, bv, acc[et], 0, 0, 0);
            }
        }
    }

    // float4 epilogue: m = m0 + w*16 + fr (row), e = e0 + et*16 + fq*4 (+i)
    float* ob = O + (size_t)(m0 + w * 16 + fr) * ND + e0 + fq * 4;
    #pragma unroll
    for (int et = 0; et < 4; ++et)
        *(f32x4*)(ob + et * 16) = acc[et];
}

// ---------------- Kernel 2a: S = tok @ v^T (R7 verbatim) --------------------
__global__ __launch_bounds__(256, 3) void s_kernel(
    const int* __restrict__ spk, const float* __restrict__ tok,
    const float* __restrict__ vws, ushort* __restrict__ S_ws, int cap)
{
    __shared__ int mlist[NT];
    __shared__ int wavecnt[4];
    __shared__ ushort At[2][4096];   // tok slab [64 l][64 d] bf16, swizzled
    __shared__ ushort Vt[2][4096];   // v   slab [64 j][64 d] bf16, swizzled
    __shared__ ushort Sb[4096];      // S [64 l][64 j] bf16, swizzled

    const int bt  = blockIdx.x;
    const int b   = bt >> 8;
    const int t   = bt & 255;
    const int tid = threadIdx.x;

    const int tgt = spk[b * NT + t];
    int my = -1;
    if (tid <= t) my = spk[b * NT + tid];
    const bool match = (tid <= t) && (my == tgt);
    unsigned long long bal = __ballot(match);
    const int lane = tid & 63, w = tid >> 6;
    if (lane == 0) wavecnt[w] = __popcll(bal);
    __syncthreads();
    int off = 0;
    #pragma unroll
    for (int ww = 0; ww < 4; ++ww) if (ww < w) off += wavecnt[ww];
    const int n = wavecnt[0] + wavecnt[1] + wavecnt[2] + wavecnt[3];
    const int before = __popcll(bal & ((1ull << lane) - 1ull));
    if (match) mlist[off + before] = tid;
    __syncthreads();

    const int fr = lane & 15;
    const int fq = lane >> 4;
    const int rb = tid >> 4;       // staging row base (0..15)
    const int c4 = tid & 15;       // staging float4 col

    const size_t tokbase = (size_t)bt * NL * ND;
    const float* vbase = vws + (size_t)b * NT * ND;
    const f32x4 z4 = {0.f, 0.f, 0.f, 0.f};

    const int nchunk = min((n + 63) >> 6, cap);
    for (int cc = 0; cc < nchunk; ++cc) {
        const int j0 = cc * 64;
        int gr[4];
        #pragma unroll
        for (int p = 0; p < 4; ++p) {
            const int jj = j0 + rb + 16 * p;
            gr[p] = mlist[jj < n ? jj : n - 1];
        }
        float4 ta[4], va[4];
        #pragma unroll
        for (int p = 0; p < 4; ++p) {
            ta[p] = *(const float4*)(tok + tokbase + (size_t)(rb + 16 * p) * ND + c4 * 4);
            va[p] = *(const float4*)(vbase + (size_t)gr[p] * ND + c4 * 4);
        }
        f32x4 accS[4];
        #pragma unroll
        for (int jt = 0; jt < 4; ++jt) accS[jt] = z4;

        for (int dt = 0; dt < 12; ++dt) {
            const int cur = dt & 1;
            #pragma unroll
            for (int p = 0; p < 4; ++p) {
                const int row = rb + 16 * p;
                const int uidx = (row * 64 + c4 * 4) ^ ((row & 7) << 3);
                uint2 tw; tw.x = pack2(ta[p].x, ta[p].y); tw.y = pack2(ta[p].z, ta[p].w);
                uint2 vw; vw.x = pack2(va[p].x, va[p].y); vw.y = pack2(va[p].z, va[p].w);
                *(uint2*)&At[cur][uidx] = tw;
                *(uint2*)&Vt[cur][uidx] = vw;
            }
            if (dt < 11) {
                const int c0 = (dt + 1) * 64 + c4 * 4;
                #pragma unroll
                for (int p = 0; p < 4; ++p) {
                    ta[p] = *(const float4*)(tok + tokbase + (size_t)(rb + 16 * p) * ND + c0);
                    va[p] = *(const float4*)(vbase + (size_t)gr[p] * ND + c0);
                }
            }
            __syncthreads();
            const int arow = w * 16 + fr;
            #pragma unroll
            for (int ks = 0; ks < 2; ++ks) {
                bf16x8 af = *(const bf16x8*)&At[cur][(arow * 64 + ks * 32 + fq * 8) ^ ((arow & 7) << 3)];
                #pragma unroll
                for (int jt = 0; jt < 4; ++jt) {
                    const int brow = jt * 16 + fr;
                    bf16x8 bv = *(const bf16x8*)&Vt[cur][(brow * 64 + ks * 32 + fq * 8) ^ ((brow & 7) << 3)];
                    accS[jt] = __builtin_amdgcn_mfma_f32_16x16x32_bf16(af, bv, accS[jt], 0, 0, 0);
                }
            }
        }

        #pragma unroll
        for (int jt = 0; jt < 4; ++jt) {
            #pragma unroll
            for (int i = 0; i < 4; ++i) {
                const int r = w * 16 + fq * 4 + i;
                const int c = jt * 16 + fr;
                Sb[(r * 64 + c) ^ ((r & 7) << 3)] = (ushort)f2bs(accS[jt][i]);
            }
        }
        __syncthreads();
        ushort* dst = S_ws + ((size_t)bt * 4 + cc) * 4096;
        #pragma unroll
        for (int g = 0; g < 2; ++g) {
            const int wsg = g * 256 + tid;
            const int r = wsg >> 3, c8 = wsg & 7;
            *(f32x4*)&dst[(size_t)wsg * 8] = *(const f32x4*)&Sb[(r * 64 + c8 * 8) ^ ((r & 7) << 3)];
        }
        __syncthreads();
    }
}

// ---------------- Kernel 2b: out = tok + S @ K, swapped operands ------------
// A=kT (i=dcol), B=S (j=l)  ->  lane holds 4 consecutive dcols of one row l:
// float4 residual loads + float4 stores.
__global__ __launch_bounds__(256, 4) void b_kernel(
    const int* __restrict__ spk, const float* __restrict__ tok,
    const float* __restrict__ kws, const ushort* __restrict__ S_ws,
    float* __restrict__ out, int cap)
{
    __shared__ int mlist[NT];
    __shared__ int wavecnt[4];
    __shared__ ushort Sb[4096];    // S bf16 [64 l][64 j], swizzled
    __shared__ ushort kT[8192];    // kT bf16 [128 dc][64 j], swizzled

    const int bt  = blockIdx.x;
    const int st  = blockIdx.y;
    const int b   = bt >> 8;
    const int t   = bt & 255;
    const int tid = threadIdx.x;
    const int lane = tid & 63, w = tid >> 6;
    const int fr = lane & 15;
    const int fq = lane >> 4;

    const size_t tokbase = (size_t)bt * NL * ND;

    // residual float4 loads, issued before everything (independent)
    f32x4 acco[8];
    {
        const float* rbp = tok + tokbase + (size_t)(w * 16 + fr) * ND + st * 128 + fq * 4;
        #pragma unroll
        for (int ct = 0; ct < 8; ++ct)
            acco[ct] = *(const f32x4*)(rbp + ct * 16);
    }

    const int tgt = spk[b * NT + t];
    int my = -1;
    if (tid <= t) my = spk[b * NT + tid];
    const bool match = (tid <= t) && (my == tgt);
    unsigned long long bal = __ballot(match);
    if (lane == 0) wavecnt[w] = __popcll(bal);
    __syncthreads();
    int off = 0;
    #pragma unroll
    for (int ww = 0; ww < 4; ++ww) if (ww < w) off += wavecnt[ww];
    const int n = wavecnt[0] + wavecnt[1] + wavecnt[2] + wavecnt[3];
    const int before = __popcll(bal & ((1ull << lane) - 1ull));
    if (match) mlist[off + before] = tid;
    __syncthreads();

    const int jr = tid >> 2;       // k-row owner (0..63)
    const int q  = tid & 3;        // 4 lanes cover one 64B line
    const float* kbase = kws + (size_t)b * NT * ND;
    const f32x4 zf = {0.f, 0.f, 0.f, 0.f};

    const int nchunk = min((n + 63) >> 6, cap);
    for (int cc = 0; cc < nchunk; ++cc) {
        const int j0 = cc * 64;
        const ushort* src = S_ws + ((size_t)bt * 4 + cc) * 4096;
        f32x4 sv0 = *(const f32x4*)&src[(size_t)tid * 8];
        f32x4 sv1 = *(const f32x4*)&src[(size_t)(256 + tid) * 8];
        const int jj = j0 + jr;
        const int g = (jj < n) ? mlist[jj] : -1;
        f32x4 kreg[8];
        #pragma unroll
        for (int p = 0; p < 8; ++p)
            kreg[p] = (g >= 0)
                ? *(const f32x4*)(kbase + (size_t)g * ND + st * 128 + (q + 4 * p) * 4)
                : zf;

        if (cc > 0) __syncthreads();
        {
            int wsg = tid, r = wsg >> 3, c8 = wsg & 7;
            *(f32x4*)&Sb[(r * 64 + c8 * 8) ^ ((r & 7) << 3)] = sv0;
            wsg = 256 + tid; r = wsg >> 3; c8 = wsg & 7;
            *(f32x4*)&Sb[(r * 64 + c8 * 8) ^ ((r & 7) << 3)] = sv1;
        }
        #pragma unroll
        for (int p = 0; p < 8; ++p) {
            #pragma unroll
            for (int e = 0; e < 4; ++e) {
                const int dc = (q + 4 * p) * 4 + e;
                kT[(dc * 64 + jr) ^ ((dc & 7) << 3)] = (ushort)f2bs(kreg[p][e]);
            }
        }
        __syncthreads();

        const int srow = w * 16 + fr;          // B = S rows (l)
        const int ssw  = (srow & 7) << 3;
        #pragma unroll
        for (int ks = 0; ks < 2; ++ks) {
            bf16x8 bv = *(const bf16x8*)&Sb[(srow * 64 + ks * 32 + fq * 8) ^ ssw];
            #pragma unroll
            for (int ct = 0; ct < 8; ++ct) {
                const int drow = ct * 16 + fr; // A = kT rows (dcol)
                bf16x8 af = *(const bf16x8*)&kT[(drow * 64 + ks * 32 + fq * 8) ^ ((drow & 7) << 3)];
                acco[ct] = __builtin_amdgcn_mfma_f32_16x16x32_bf16(af, bv, acco[ct], 0, 0, 0);
            }
        }
    }

    // float4 stores: row l = w*16+fr, dcol = st*128 + ct*16 + fq*4 (+i)
    float* ob = out + tokbase + (size_t)(w * 16 + fr) * ND + st * 128 + fq * 4;
    #pragma unroll
    for (int ct = 0; ct < 8; ++ct)
        *(f32x4*)(ob + ct * 16) = acco[ct];
}

extern "C" void kernel_launch(void* const* d_in, const int* in_sizes, int n_in,
                              void* d_out, int out_size, void* d_ws, size_t ws_size,
                              hipStream_t stream) {
    const int*   spk = (const int*)d_in[1];
    const float* tok = (const float*)d_in[2];
    const float* edu = (const float*)d_in[3];
    const float* Wk  = (const float*)d_in[4];
    const float* Wv  = (const float*)d_in[5];

    const size_t kv_floats = (size_t)NB * NT * ND;
    float* kws = (float*)d_ws;
    float* vws = kws + kv_floats;
    ushort* S_ws = (ushort*)(vws + kv_floats);
    const size_t s_bytes_per_chunkset = (size_t)NB * NT * 4096ull * 2ull;
    size_t avail = (ws_size > 2 * kv_floats * 4) ? (ws_size - 2 * kv_floats * 4) : 0;
    int cap = (int)(avail / s_bytes_per_chunkset);
    if (cap > 4) cap = 4;
    if (cap < 1) cap = 1;
    float* outp = (float*)d_out;

    projm_kernel<<<dim3(2048 / 64, ND / 64, 2), 256, 0, stream>>>(edu, Wk, Wv, kws, vws);
    s_kernel<<<NB * NT, 256, 0, stream>>>(spk, tok, vws, S_ws, cap);
    b_kernel<<<dim3(NB * NT, 6), 256, 0, stream>>>(spk, tok, kws, S_ws, outp, cap);
}